// Round 2
// baseline (19418.939 us; speedup 1.0000x reference)
//
#include <hip/hip_runtime.h>
#include <hip/hip_bf16.h>
#include <math.h>

typedef __hip_bfloat16 bf16;

#define D_    512
#define H_    4
#define DH_   128
#define L_    4
#define FF_   512
#define B_    64
#define NH_   6
#define S_    256
#define T_    64
#define IMG_  2048

__device__ __forceinline__ float toF(bf16 v)  { return __bfloat162float(v); }
__device__ __forceinline__ float toF(float v) { return v; }
__device__ __forceinline__ void storeF(bf16* p, float v)  { *p = __float2bfloat16(v); }
__device__ __forceinline__ void storeF(float* p, float v) { *p = v; }

// x[row, d] = emb[tokens[row], d] + pe[row % Tt, d]   (fp32 out)
__global__ void embed_kernel(const int* __restrict__ tokens,
                             const float* __restrict__ emb,
                             float* __restrict__ x,
                             int Tt, int total) {
    int idx = blockIdx.x * blockDim.x + threadIdx.x;
    if (idx >= total) return;
    int d   = idx & (D_ - 1);
    int row = idx >> 9;
    int t   = row % Tt;
    int tok = tokens[row];
    int i   = d >> 1;
    // div = exp(-(2i) * ln(10000)/512)
    float ex  = -(float)(2 * i) * (9.210340371976184f / 512.0f);
    float dv  = expf(ex);
    float ang = (float)t * dv;
    float pe  = (d & 1) ? cosf(ang) : sinf(ang);
    x[idx] = emb[(size_t)tok * D_ + d] + pe;
}

// C[M,N] = A[M,K] @ Bw[K,N] + bias[N] (+ C if addC) (relu?)  fp32 accumulate
// M % 64 == 0, N % 64 == 0, K % 16 == 0.  In-place addC is safe: each element
// is read then written by exactly one thread.
template <typename AT, typename CT>
__global__ __launch_bounds__(256) void gemm_kernel(
    const AT* __restrict__ A, const float* __restrict__ Bw,
    const float* __restrict__ bias,
    CT* __restrict__ C, int M, int K, int N, int addC, int relu) {
    __shared__ float As[64][17];
    __shared__ float Bs[16][65];
    int tid  = threadIdx.x;
    int row0 = blockIdx.y * 64;
    int col0 = blockIdx.x * 64;
    int ty = tid >> 4, tx = tid & 15;
    float acc[4][4] = {};
    for (int kt = 0; kt < K; kt += 16) {
#pragma unroll
        for (int j = 0; j < 4; ++j) {
            int idx = tid * 4 + j;          // 0..1023
            int r = idx >> 4, c = idx & 15;
            As[r][c] = toF(A[(size_t)(row0 + r) * K + kt + c]);
        }
#pragma unroll
        for (int j = 0; j < 4; ++j) {
            int idx = tid * 4 + j;
            int r = idx >> 6, c = idx & 63;
            Bs[r][c] = Bw[(size_t)(kt + r) * N + col0 + c];
        }
        __syncthreads();
#pragma unroll
        for (int kk = 0; kk < 16; ++kk) {
            float a[4], b[4];
#pragma unroll
            for (int i = 0; i < 4; ++i) a[i] = As[ty * 4 + i][kk];
#pragma unroll
            for (int j = 0; j < 4; ++j) b[j] = Bs[kk][tx * 4 + j];
#pragma unroll
            for (int i = 0; i < 4; ++i)
#pragma unroll
                for (int j = 0; j < 4; ++j) acc[i][j] += a[i] * b[j];
        }
        __syncthreads();
    }
#pragma unroll
    for (int i = 0; i < 4; ++i) {
        int r = row0 + ty * 4 + i;
#pragma unroll
        for (int j = 0; j < 4; ++j) {
            int c = col0 + tx * 4 + j;
            float v = acc[i][j] + bias[c];
            if (addC) v += toF(C[(size_t)r * N + c]);
            if (relu) v = fmaxf(v, 0.f);
            storeF(&C[(size_t)r * N + c], v);
        }
    }
}

// One block per (m, h, qi): scores + mask + softmax, write probs (bf16).
// blockDim.x == Tt (64 or 256)
__global__ void attn_softmax_kernel(const bf16* __restrict__ q,
                                    const bf16* __restrict__ k,
                                    bf16* __restrict__ p,
                                    const int* __restrict__ lens,
                                    int M, int Tt) {
    int bid = blockIdx.x;
    int qi  = bid % Tt;
    int h   = (bid / Tt) % H_;
    int m   = bid / (Tt * H_);
    int t   = threadIdx.x;  // key index
    __shared__ float qs[DH_];
    __shared__ float red[256];
    for (int d = t; d < DH_; d += blockDim.x)
        qs[d] = toF(q[(size_t)(m * Tt + qi) * D_ + h * DH_ + d]);
    __syncthreads();
    int kvalid = Tt;
    if (lens) { int l0 = lens[m]; kvalid = l0 < 1 ? 1 : l0; }
    const bf16* krow = k + (size_t)(m * Tt + t) * D_ + h * DH_;
    float s = 0.f;
    for (int d = 0; d < DH_; ++d) s += qs[d] * toF(krow[d]);
    s *= 0.08838834764831845f;  // 1/sqrt(128)
    bool valid = (t < kvalid);
    red[t] = valid ? s : -INFINITY;
    __syncthreads();
    for (int off = blockDim.x / 2; off > 0; off >>= 1) {
        if (t < off) red[t] = fmaxf(red[t], red[t + off]);
        __syncthreads();
    }
    float mx = red[0];
    __syncthreads();
    float e = valid ? expf(s - mx) : 0.f;
    red[t] = e;
    __syncthreads();
    for (int off = blockDim.x / 2; off > 0; off >>= 1) {
        if (t < off) red[t] += red[t + off];
        __syncthreads();
    }
    p[(size_t)bid * Tt + t] = __float2bfloat16(e / red[0]);
}

// One block per (m, h, qi), DH_ threads: ctx = probs @ V
__global__ void attn_ctx_kernel(const bf16* __restrict__ p,
                                const bf16* __restrict__ v,
                                bf16* __restrict__ out,
                                int M, int Tt) {
    int bid = blockIdx.x;
    int qi  = bid % Tt;
    int h   = (bid / Tt) % H_;
    int m   = bid / (Tt * H_);
    int dh  = threadIdx.x;
    const bf16* prow = p + (size_t)bid * Tt;
    float acc = 0.f;
    for (int t = 0; t < Tt; ++t)
        acc += toF(prow[t]) * toF(v[(size_t)(m * Tt + t) * D_ + h * DH_ + dh]);
    out[(size_t)(m * Tt + qi) * D_ + h * DH_ + dh] = __float2bfloat16(acc);
}

// One block (256 threads) per row: x = LN(x)*g + b  in place (fp32)
__global__ void ln_kernel(float* __restrict__ x,
                          const float* __restrict__ g,
                          const float* __restrict__ b) {
    int row = blockIdx.x;
    int t   = threadIdx.x;
    __shared__ float red[256];
    float v0 = x[(size_t)row * D_ + t];
    float v1 = x[(size_t)row * D_ + t + 256];
    red[t] = v0 + v1;
    __syncthreads();
    for (int off = 128; off > 0; off >>= 1) {
        if (t < off) red[t] += red[t + off];
        __syncthreads();
    }
    float mu = red[0] / 512.f;
    __syncthreads();
    float d0 = v0 - mu, d1 = v1 - mu;
    red[t] = d0 * d0 + d1 * d1;
    __syncthreads();
    for (int off = 128; off > 0; off >>= 1) {
        if (t < off) red[t] += red[t + off];
        __syncthreads();
    }
    float inv = rsqrtf(red[0] / 512.f + 1e-5f);
    x[(size_t)row * D_ + t]       = d0 * inv * g[t] + b[t];
    x[(size_t)row * D_ + t + 256] = d1 * inv * g[t + 256] + b[t + 256];
}

__global__ void copy_last_main(const float* __restrict__ x, float* __restrict__ bh) {
    int idx = blockIdx.x * blockDim.x + threadIdx.x;  // 64*512
    int b = idx >> 9, d = idx & 511;
    bh[idx] = x[(size_t)(b * S_ + S_ - 1) * D_ + d];
}

__global__ void add_last_kernel(const float* __restrict__ x,
                                const int* __restrict__ lens,
                                float* __restrict__ sep) {
    int idx = blockIdx.x * blockDim.x + threadIdx.x;  // 384*512
    int bn = idx >> 9, d = idx & 511;
    int len = lens[bn];
    float add = (len > 0) ? x[(size_t)(bn * T_ + len - 1) * D_ + d] : 0.f;
    sep[idx] += add;
}

// One block per (b,n): optional relu+normalize, dot with batch_hidden
__global__ void final_kernel(const float* __restrict__ sep,
                             const float* __restrict__ bh,
                             const int* __restrict__ nflag,
                             float* __restrict__ out) {
    int bn = blockIdx.x;
    int b  = bn / NH_;
    int t  = threadIdx.x;  // 256
    __shared__ float red[256];
    float v0 = sep[(size_t)bn * D_ + t];
    float v1 = sep[(size_t)bn * D_ + t + 256];
    int nf = nflag[0];
    float scale = 1.f;
    if (nf) {
        v0 = fmaxf(v0, 0.f);
        v1 = fmaxf(v1, 0.f);
        red[t] = v0 * v0 + v1 * v1;
        __syncthreads();
        for (int off = 128; off > 0; off >>= 1) {
            if (t < off) red[t] += red[t + off];
            __syncthreads();
        }
        scale = 1.f / fmaxf(sqrtf(red[0]), 1e-12f);
        __syncthreads();
    }
    red[t] = v0 * scale * bh[(size_t)b * D_ + t] + v1 * scale * bh[(size_t)b * D_ + t + 256];
    __syncthreads();
    for (int off = 128; off > 0; off >>= 1) {
        if (t < off) red[t] += red[t + off];
        __syncthreads();
    }
    if (t == 0) out[bn] = red[0];
}

extern "C" void kernel_launch(void* const* d_in, const int* in_sizes, int n_in,
                              void* d_out, int out_size, void* d_ws, size_t ws_size,
                              hipStream_t stream) {
    const int*   segment   = (const int*)d_in[0];
    const int*   prev_hist = (const int*)d_in[1];
    const int*   lens      = (const int*)d_in[2];
    const float* sep_img   = (const float*)d_in[3];
    const int*   normalize = (const int*)d_in[4];
    const float* emb       = (const float*)d_in[5];
    const float* Wq = (const float*)d_in[6];
    const float* bq = (const float*)d_in[7];
    const float* Wk = (const float*)d_in[8];
    const float* bk = (const float*)d_in[9];
    const float* Wv = (const float*)d_in[10];
    const float* bv = (const float*)d_in[11];
    const float* Wo = (const float*)d_in[12];
    const float* bo = (const float*)d_in[13];
    const float* ln1g = (const float*)d_in[14];
    const float* ln1b = (const float*)d_in[15];
    const float* W1 = (const float*)d_in[16];
    const float* b1 = (const float*)d_in[17];
    const float* W2 = (const float*)d_in[18];
    const float* b2 = (const float*)d_in[19];
    const float* ln2g = (const float*)d_in[20];
    const float* ln2b = (const float*)d_in[21];
    const float* Wsep = (const float*)d_in[22];
    const float* bsep = (const float*)d_in[23];
    float* out = (float*)d_out;

    // workspace layout (~153 MB)
    const size_t NTmax = 384 * 64;  // 24576 (>= 64*256)
    char* w = (char*)d_ws;
    float* xb   = (float*)w; w += (size_t)NTmax * D_ * 4;          // 50.3 MB
    float* bh   = (float*)w; w += (size_t)B_ * D_ * 4;
    float* sepb = (float*)w; w += (size_t)B_ * NH_ * D_ * 4;
    bf16* qb = (bf16*)w;  w += (size_t)NTmax * D_ * 2;             // 25.2 MB
    bf16* kb = (bf16*)w;  w += (size_t)NTmax * D_ * 2;
    bf16* vb = (bf16*)w;  w += (size_t)NTmax * D_ * 2;
    bf16* sb = (bf16*)w;  w += (size_t)B_ * H_ * S_ * S_ * 2;      // 33.6 MB

    auto run_encoder = [&](int M, int Tt, const int* lens_p) {
        int NT = M * Tt;
        dim3 gg(D_ / 64, NT / 64);
        for (int l = 0; l < L_; ++l) {
            gemm_kernel<float, bf16><<<gg, 256, 0, stream>>>(
                xb, Wq + (size_t)l * D_ * D_, bq + l * D_, qb, NT, D_, D_, 0, 0);
            gemm_kernel<float, bf16><<<gg, 256, 0, stream>>>(
                xb, Wk + (size_t)l * D_ * D_, bk + l * D_, kb, NT, D_, D_, 0, 0);
            gemm_kernel<float, bf16><<<gg, 256, 0, stream>>>(
                xb, Wv + (size_t)l * D_ * D_, bv + l * D_, vb, NT, D_, D_, 0, 0);
            attn_softmax_kernel<<<M * H_ * Tt, Tt, 0, stream>>>(qb, kb, sb, lens_p, M, Tt);
            attn_ctx_kernel<<<M * H_ * Tt, DH_, 0, stream>>>(sb, vb, qb, M, Tt);  // ctx -> qb
            gemm_kernel<bf16, float><<<gg, 256, 0, stream>>>(
                qb, Wo + (size_t)l * D_ * D_, bo + l * D_, xb, NT, D_, D_, 1, 0);
            ln_kernel<<<NT, 256, 0, stream>>>(xb, ln1g + l * D_, ln1b + l * D_);
            gemm_kernel<float, bf16><<<gg, 256, 0, stream>>>(
                xb, W1 + (size_t)l * D_ * FF_, b1 + l * FF_, qb, NT, D_, FF_, 0, 1);
            gemm_kernel<bf16, float><<<gg, 256, 0, stream>>>(
                qb, W2 + (size_t)l * FF_ * D_, b2 + l * D_, xb, NT, FF_, D_, 1, 0);
            ln_kernel<<<NT, 256, 0, stream>>>(xb, ln2g + l * D_, ln2b + l * D_);
        }
    };

    // ---- main encoder: M=64, Tt=256, no mask ----
    {
        int total = B_ * S_ * D_;
        embed_kernel<<<total / 256, 256, 0, stream>>>(segment, emb, xb, S_, total);
    }
    run_encoder(B_, S_, nullptr);
    copy_last_main<<<(B_ * D_) / 256, 256, 0, stream>>>(xb, bh);

    // ---- sep = separate_images @ Wsep + bsep : (384 x 2048) @ (2048 x 512) ----
    {
        dim3 gg(FF_ / 64, (B_ * NH_) / 64);
        gemm_kernel<float, float><<<gg, 256, 0, stream>>>(
            sep_img, Wsep, bsep, sepb, B_ * NH_, IMG_, FF_, 0, 0);
    }

    // ---- history encoder: M=384, Tt=64, key mask from lens ----
    {
        int total = B_ * NH_ * T_ * D_;
        embed_kernel<<<total / 256, 256, 0, stream>>>(prev_hist, emb, xb, T_, total);
    }
    run_encoder(B_ * NH_, T_, lens);

    add_last_kernel<<<(B_ * NH_ * D_) / 256, 256, 0, stream>>>(xb, lens, sepb);
    final_kernel<<<B_ * NH_, 256, 0, stream>>>(sepb, bh, normalize, out);
}

// Round 4
// 3258.961 us; speedup vs baseline: 5.9586x; 5.9586x over previous
//
#include <hip/hip_runtime.h>
#include <hip/hip_bf16.h>
#include <math.h>

typedef __hip_bfloat16 bf16;
typedef __attribute__((ext_vector_type(8))) short short8;
typedef __attribute__((ext_vector_type(4))) float f32x4;

#define D_    512
#define H_    4
#define DH_   128
#define L_    4
#define FF_   512
#define B_    64
#define NH_   6
#define S_    256
#define T_    64
#define IMG_  2048

__device__ __forceinline__ float toF(bf16 v)  { return __bfloat162float(v); }
__device__ __forceinline__ float toF(float v) { return v; }
__device__ __forceinline__ void storeF(bf16* p, float v)  { *p = __float2bfloat16(v); }
__device__ __forceinline__ void storeF(float* p, float v) { *p = v; }

// round-to-nearest-even f32 -> bf16 bits
__device__ __forceinline__ unsigned short f2b(float f) {
    unsigned u = __float_as_uint(f);
    unsigned r = (u + 0x7fffu + ((u >> 16) & 1u)) >> 16;
    return (unsigned short)r;
}
__device__ __forceinline__ unsigned packbf(float a, float b) {
    return (unsigned)f2b(a) | ((unsigned)f2b(b) << 16);
}

// ---- weight transpose + cast: src[R][C] fp32 -> dst[C][R] bf16, z = layer ----
__global__ void transpose_cast(const float* __restrict__ src, bf16* __restrict__ dst,
                               int R, int Cc) {
    __shared__ float t[32][33];
    size_t off = (size_t)blockIdx.z * R * Cc;
    src += off; dst += off;
    int c0 = blockIdx.x * 32, r0 = blockIdx.y * 32;
    int tx = threadIdx.x & 31, ty = threadIdx.x >> 5;  // 256 thr: ty 0..7
    for (int i = ty; i < 32; i += 8) t[i][tx] = src[(size_t)(r0 + i) * Cc + c0 + tx];
    __syncthreads();
    for (int i = ty; i < 32; i += 8)
        dst[(size_t)(c0 + i) * R + r0 + tx] = __float2bfloat16(t[tx][i]);
}

// ---- flat f32 -> bf16 cast ----
__global__ void cast_bf16(const float* __restrict__ src, bf16* __restrict__ dst, int n) {
    int i = blockIdx.x * blockDim.x + threadIdx.x;
    if (i < n) dst[i] = __float2bfloat16(src[i]);
}

// ---- embedding + positional encoding: fp32 x and bf16 mirror ----
__global__ void embed_kernel(const int* __restrict__ tokens,
                             const float* __restrict__ emb,
                             float* __restrict__ x, bf16* __restrict__ x16,
                             int Tt, int total) {
    int idx = blockIdx.x * blockDim.x + threadIdx.x;
    if (idx >= total) return;
    int d   = idx & (D_ - 1);
    int row = idx >> 9;
    int t   = row % Tt;
    int tok = tokens[row];
    int i   = d >> 1;
    float ex  = -(float)(2 * i) * (9.210340371976184f / 512.0f);
    float dv  = expf(ex);
    float ang = (float)t * dv;
    float pe  = (d & 1) ? cosf(ang) : sinf(ang);
    float v = emb[(size_t)tok * D_ + d] + pe;
    x[idx] = v;
    x16[idx] = __float2bfloat16(v);
}

// ---- MFMA bf16 GEMM: C[M,N] = A[M,K] @ B[K,N] + bias, B given transposed Bt[N][K]
// 128x128 tile, BK=64, 4 waves each computing 64x64 via 4x4 MFMAs 16x16x32.
// lt >= 0: head-major bf16 out (qkv): out[((m*H+h)*Tt + qi)*128 + dh], Tt = 1<<lt
// lt < 0 : row-major, optional addC (in-place +=) and relu.
template <typename CT>
__global__ __launch_bounds__(256) void gemm_mfma(
    const bf16* __restrict__ A, const bf16* __restrict__ Bt,
    const float* __restrict__ bias, CT* __restrict__ C,
    int M, int N, int K, int lt, int relu, int addC) {
    __shared__ short As[128][72];   // +8 shorts pad: 16B-aligned rows, 2-way-max banks
    __shared__ short Bs[128][72];
    int tid  = threadIdx.x;
    int wave = tid >> 6, lane = tid & 63, lr = lane & 15, quad = lane >> 4;
    int wr = (wave >> 1) * 64, wc = (wave & 1) * 64;
    int row0 = blockIdx.y * 128, col0 = blockIdx.x * 128;
    f32x4 acc[4][4];
    f32x4 zz = {0.f, 0.f, 0.f, 0.f};
#pragma unroll
    for (int mi = 0; mi < 4; ++mi)
#pragma unroll
        for (int ni = 0; ni < 4; ++ni) acc[mi][ni] = zz;

    for (int kt = 0; kt < K; kt += 64) {
        // stage 128x64 bf16 tiles: 1024 chunks of 8 shorts (16B), 4 per thread
#pragma unroll
        for (int ee = 0; ee < 4; ++ee) {
            int e = tid + ee * 256;       // 0..1023
            int r = e >> 3, c = (e & 7) * 8;
            *(short8*)&As[r][c] = *(const short8*)&A[(size_t)(row0 + r) * K + kt + c];
            *(short8*)&Bs[r][c] = *(const short8*)&Bt[(size_t)(col0 + r) * K + kt + c];
        }
        __syncthreads();
#pragma unroll
        for (int kk = 0; kk < 64; kk += 32) {
            short8 af[4], bf4[4];
#pragma unroll
            for (int mi = 0; mi < 4; ++mi)
                af[mi] = *(const short8*)&As[wr + mi * 16 + lr][kk + quad * 8];
#pragma unroll
            for (int ni = 0; ni < 4; ++ni)
                bf4[ni] = *(const short8*)&Bs[wc + ni * 16 + lr][kk + quad * 8];
#pragma unroll
            for (int mi = 0; mi < 4; ++mi)
#pragma unroll
                for (int ni = 0; ni < 4; ++ni)
                    acc[mi][ni] = __builtin_amdgcn_mfma_f32_16x16x32_bf16(
                        af[mi], bf4[ni], acc[mi][ni], 0, 0, 0);
        }
        __syncthreads();
    }
    int Ttm1 = (lt >= 0) ? ((1 << lt) - 1) : 0;
#pragma unroll
    for (int ni = 0; ni < 4; ++ni) {
        int gc = col0 + wc + ni * 16 + lr;
        float bi = bias[gc];
#pragma unroll
        for (int mi = 0; mi < 4; ++mi) {
            int gr0 = row0 + wr + mi * 16 + quad * 4;
            f32x4 vv = acc[mi][ni];
#pragma unroll
            for (int rr = 0; rr < 4; ++rr) {
                int r = gr0 + rr;
                float val = vv[rr] + bi;
                if (lt >= 0) {
                    int h2 = gc >> 7, dh = gc & 127;
                    int mq = r >> lt, qi = r & Ttm1;
                    size_t oi = ((((size_t)(mq * H_ + h2)) << lt) + qi) * DH_ + dh;
                    storeF(&C[oi], val);
                } else {
                    size_t oi = (size_t)r * N + gc;
                    if (addC) val += toF(C[oi]);
                    if (relu) val = fmaxf(val, 0.f);
                    storeF(&C[oi], val);
                }
            }
        }
    }
}

// ---- fused flash attention: block per (m, h, 64-query tile), 256 threads ----
// q/k/v head-major [mh][Tt][128] bf16; ctx row-major [M*Tt][512] bf16.
__global__ __launch_bounds__(256) void fused_attn(
    const bf16* __restrict__ q, const bf16* __restrict__ k, const bf16* __restrict__ v,
    bf16* __restrict__ ctx, const int* __restrict__ lens, int Tt, int nqt) {
    __shared__ unsigned Qs[64][65];   // 64 queries x 128 bf16 (packed pairs) +1 pad
    __shared__ unsigned Ks[64][65];
    __shared__ unsigned Vs[64][64];   // unpadded; uint4 reads are 2-way max
    __shared__ unsigned Ps[64][33];   // P tile bf16-packed
    __shared__ float red[64][17];
    __shared__ float mrow[64], lrow[64], arow[64];
    int bx = blockIdx.x;
    int qt = bx % nqt, mh = bx / nqt;
    int m = mh >> 2, h = mh & 3;
    int tid = threadIdx.x;
    int ty = tid >> 4, tx = tid & 15;
    int kvalid = Tt;
    if (lens) { int l0 = lens[m]; kvalid = l0 < 1 ? 1 : l0; }

    const unsigned* qg = (const unsigned*)(q + ((size_t)mh * Tt + qt * 64) * DH_);
    for (int e = tid; e < 4096; e += 256) Qs[e >> 6][e & 63] = qg[e];
    if (tid < 64) { mrow[tid] = -INFINITY; lrow[tid] = 0.f; }
    float acc[4][8] = {};
    int nkt = Tt >> 6;
    for (int kt = 0; kt < nkt; ++kt) {
        __syncthreads();  // guards Q stage (1st iter) and prev-iter Vs/Ps reads
        const unsigned* kg = (const unsigned*)(k + ((size_t)mh * Tt + kt * 64) * DH_);
        const unsigned* vg = (const unsigned*)(v + ((size_t)mh * Tt + kt * 64) * DH_);
        for (int e = tid; e < 4096; e += 256) {
            Ks[e >> 6][e & 63] = kg[e];
            Vs[e >> 6][e & 63] = vg[e];
        }
        __syncthreads();
        // ---- S = Q K^T (64x64), thread owns 4 queries x 4 keys ----
        float s[4][4] = {};
        for (int ku = 0; ku < 64; ++ku) {
            float ax[4], ay[4], bx2[4], by2[4];
#pragma unroll
            for (int i = 0; i < 4; ++i) {
                unsigned u = Qs[ty * 4 + i][ku];
                ax[i] = __uint_as_float(u << 16);
                ay[i] = __uint_as_float(u & 0xffff0000u);
            }
#pragma unroll
            for (int j = 0; j < 4; ++j) {
                unsigned u = Ks[tx * 4 + j][ku];
                bx2[j] = __uint_as_float(u << 16);
                by2[j] = __uint_as_float(u & 0xffff0000u);
            }
#pragma unroll
            for (int i = 0; i < 4; ++i)
#pragma unroll
                for (int j = 0; j < 4; ++j)
                    s[i][j] += ax[i] * bx2[j] + ay[i] * by2[j];
        }
        int kb = kt * 64;
        // ---- per-query tile max ----
#pragma unroll
        for (int i = 0; i < 4; ++i) {
            float mx = -INFINITY;
#pragma unroll
            for (int j = 0; j < 4; ++j) {
                s[i][j] *= 0.08838834764831845f;
                if (kb + tx * 4 + j >= kvalid) s[i][j] = -INFINITY;
                mx = fmaxf(mx, s[i][j]);
            }
            red[ty * 4 + i][tx] = mx;
        }
        __syncthreads();
        if (tid < 64) {
            float tm = red[tid][0];
            for (int t2 = 1; t2 < 16; ++t2) tm = fmaxf(tm, red[tid][t2]);
            float mold = mrow[tid];
            float mnew = fmaxf(mold, tm);
            arow[tid] = __expf(mold - mnew);
            mrow[tid] = mnew;
        }
        __syncthreads();
        // ---- P = exp(s - m), store bf16; partial sums ----
#pragma unroll
        for (int i = 0; i < 4; ++i) {
            int qq = ty * 4 + i;
            float mn = mrow[qq];
            float p0 = __expf(s[i][0] - mn);
            float p1 = __expf(s[i][1] - mn);
            float p2 = __expf(s[i][2] - mn);
            float p3 = __expf(s[i][3] - mn);
            Ps[qq][tx * 2]     = packbf(p0, p1);
            Ps[qq][tx * 2 + 1] = packbf(p2, p3);
            red[qq][tx] = p0 + p1 + p2 + p3;
        }
        __syncthreads();
        if (tid < 64) {
            float sm = 0.f;
            for (int t2 = 0; t2 < 16; ++t2) sm += red[tid][t2];
            lrow[tid] = lrow[tid] * arow[tid] + sm;
        }
        __syncthreads();
        // ---- rescale acc, then acc += P V ----
        float al[4];
#pragma unroll
        for (int i = 0; i < 4; ++i) al[i] = arow[ty * 4 + i];
#pragma unroll
        for (int i = 0; i < 4; ++i)
#pragma unroll
            for (int d = 0; d < 8; ++d) acc[i][d] *= al[i];
        for (int ju = 0; ju < 32; ++ju) {
            float px[4], py[4];
#pragma unroll
            for (int i = 0; i < 4; ++i) {
                unsigned u = Ps[ty * 4 + i][ju];
                px[i] = __uint_as_float(u << 16);
                py[i] = __uint_as_float(u & 0xffff0000u);
            }
            uint4 w0 = *(const uint4*)&Vs[2 * ju][tx * 4];
            uint4 w1 = *(const uint4*)&Vs[2 * ju + 1][tx * 4];
            float v0[8], v1[8];
            const unsigned* c0 = &w0.x;
            const unsigned* c1 = &w1.x;
#pragma unroll
            for (int du = 0; du < 4; ++du) {
                v0[2 * du]     = __uint_as_float(c0[du] << 16);
                v0[2 * du + 1] = __uint_as_float(c0[du] & 0xffff0000u);
                v1[2 * du]     = __uint_as_float(c1[du] << 16);
                v1[2 * du + 1] = __uint_as_float(c1[du] & 0xffff0000u);
            }
#pragma unroll
            for (int i = 0; i < 4; ++i)
#pragma unroll
                for (int d = 0; d < 8; ++d)
                    acc[i][d] += px[i] * v0[d] + py[i] * v1[d];
        }
    }
    // ---- write ctx (row-major bf16) ----
    unsigned* cg = (unsigned*)ctx;
#pragma unroll
    for (int i = 0; i < 4; ++i) {
        int qq = ty * 4 + i;
        float linv = 1.f / lrow[qq];
        size_t row = (size_t)m * Tt + qt * 64 + qq;
        size_t base = row * 256 + h * 64 + tx * 4;
#pragma unroll
        for (int du = 0; du < 4; ++du)
            cg[base + du] = packbf(acc[i][2 * du] * linv, acc[i][2 * du + 1] * linv);
    }
}

// ---- LayerNorm in place (fp32) + bf16 mirror ----
__global__ void ln_kernel(float* __restrict__ x,
                          const float* __restrict__ g,
                          const float* __restrict__ b,
                          bf16* __restrict__ x16) {
    int row = blockIdx.x;
    int t   = threadIdx.x;
    __shared__ float red[256];
    float v0 = x[(size_t)row * D_ + t];
    float v1 = x[(size_t)row * D_ + t + 256];
    red[t] = v0 + v1;
    __syncthreads();
    for (int off = 128; off > 0; off >>= 1) {
        if (t < off) red[t] += red[t + off];
        __syncthreads();
    }
    float mu = red[0] / 512.f;
    __syncthreads();
    float d0 = v0 - mu, d1 = v1 - mu;
    red[t] = d0 * d0 + d1 * d1;
    __syncthreads();
    for (int off = 128; off > 0; off >>= 1) {
        if (t < off) red[t] += red[t + off];
        __syncthreads();
    }
    float inv = rsqrtf(red[0] / 512.f + 1e-5f);
    float o0 = d0 * inv * g[t] + b[t];
    float o1 = d1 * inv * g[t + 256] + b[t + 256];
    x[(size_t)row * D_ + t]       = o0;
    x[(size_t)row * D_ + t + 256] = o1;
    x16[(size_t)row * D_ + t]       = __float2bfloat16(o0);
    x16[(size_t)row * D_ + t + 256] = __float2bfloat16(o1);
}

__global__ void copy_last_main(const float* __restrict__ x, float* __restrict__ bh) {
    int idx = blockIdx.x * blockDim.x + threadIdx.x;  // 64*512
    int b = idx >> 9, d = idx & 511;
    bh[idx] = x[(size_t)(b * S_ + S_ - 1) * D_ + d];
}

__global__ void add_last_kernel(const float* __restrict__ x,
                                const int* __restrict__ lens,
                                float* __restrict__ sep) {
    int idx = blockIdx.x * blockDim.x + threadIdx.x;  // 384*512
    int bn = idx >> 9, d = idx & 511;
    int len = lens[bn];
    float add = (len > 0) ? x[(size_t)(bn * T_ + len - 1) * D_ + d] : 0.f;
    sep[idx] += add;
}

__global__ void final_kernel(const float* __restrict__ sep,
                             const float* __restrict__ bh,
                             const int* __restrict__ nflag,
                             float* __restrict__ out) {
    int bn = blockIdx.x;
    int b  = bn / NH_;
    int t  = threadIdx.x;  // 256
    __shared__ float red[256];
    float v0 = sep[(size_t)bn * D_ + t];
    float v1 = sep[(size_t)bn * D_ + t + 256];
    int nf = nflag[0];
    float scale = 1.f;
    if (nf) {
        v0 = fmaxf(v0, 0.f);
        v1 = fmaxf(v1, 0.f);
        red[t] = v0 * v0 + v1 * v1;
        __syncthreads();
        for (int off = 128; off > 0; off >>= 1) {
            if (t < off) red[t] += red[t + off];
            __syncthreads();
        }
        scale = 1.f / fmaxf(sqrtf(red[0]), 1e-12f);
        __syncthreads();
    }
    red[t] = v0 * scale * bh[(size_t)b * D_ + t] + v1 * scale * bh[(size_t)b * D_ + t + 256];
    __syncthreads();
    for (int off = 128; off > 0; off >>= 1) {
        if (t < off) red[t] += red[t + off];
        __syncthreads();
    }
    if (t == 0) out[bn] = red[0];
}

extern "C" void kernel_launch(void* const* d_in, const int* in_sizes, int n_in,
                              void* d_out, int out_size, void* d_ws, size_t ws_size,
                              hipStream_t stream) {
    const int*   segment   = (const int*)d_in[0];
    const int*   prev_hist = (const int*)d_in[1];
    const int*   lens      = (const int*)d_in[2];
    const float* sep_img   = (const float*)d_in[3];
    const int*   normalize = (const int*)d_in[4];
    const float* emb       = (const float*)d_in[5];
    const float* Wq = (const float*)d_in[6];
    const float* bq = (const float*)d_in[7];
    const float* Wk = (const float*)d_in[8];
    const float* bk = (const float*)d_in[9];
    const float* Wv = (const float*)d_in[10];
    const float* bv = (const float*)d_in[11];
    const float* Wo = (const float*)d_in[12];
    const float* bo = (const float*)d_in[13];
    const float* ln1g = (const float*)d_in[14];
    const float* ln1b = (const float*)d_in[15];
    const float* W1 = (const float*)d_in[16];
    const float* b1 = (const float*)d_in[17];
    const float* W2 = (const float*)d_in[18];
    const float* b2 = (const float*)d_in[19];
    const float* ln2g = (const float*)d_in[20];
    const float* ln2b = (const float*)d_in[21];
    const float* Wsep = (const float*)d_in[22];
    const float* bsep = (const float*)d_in[23];
    float* out = (float*)d_out;

    // ---- workspace layout (~160.4 MiB) ----
    const size_t NTmax = 384 * 64;  // 24576 (>= 64*256)
    char* w = (char*)d_ws;
    float* xb   = (float*)w; w += (size_t)NTmax * D_ * 4;   // fp32 residual stream
    float* bh   = (float*)w; w += (size_t)B_ * D_ * 4;
    float* sepb = (float*)w; w += (size_t)B_ * NH_ * D_ * 4;
    bf16* x16 = (bf16*)w; w += (size_t)NTmax * D_ * 2;      // bf16 mirror; also ctx
    bf16* qh  = (bf16*)w; w += (size_t)NTmax * D_ * 2;      // head-major q; also ffmid
    bf16* kh  = (bf16*)w; w += (size_t)NTmax * D_ * 2;
    bf16* vh  = (bf16*)w; w += (size_t)NTmax * D_ * 2;
    bf16* sep16 = (bf16*)w; w += (size_t)B_ * NH_ * IMG_ * 2;
    bf16* Wqt = (bf16*)w; w += (size_t)L_ * D_ * D_ * 2;
    bf16* Wkt = (bf16*)w; w += (size_t)L_ * D_ * D_ * 2;
    bf16* Wvt = (bf16*)w; w += (size_t)L_ * D_ * D_ * 2;
    bf16* Wot = (bf16*)w; w += (size_t)L_ * D_ * D_ * 2;
    bf16* W1t = (bf16*)w; w += (size_t)L_ * D_ * FF_ * 2;
    bf16* W2t = (bf16*)w; w += (size_t)L_ * FF_ * D_ * 2;
    bf16* Wsept = (bf16*)w; w += (size_t)IMG_ * D_ * 2;
    bf16* ctx16 = x16;   // alias: x16 not needed between qkv-GEMMs and LN1
    bf16* ffmid = qh;    // alias: q not needed after attention

    // ---- weight conversion (every call; inputs re-poisoned by harness) ----
    {
        dim3 tg(16, 16, L_);
        transpose_cast<<<tg, 256, 0, stream>>>(Wq, Wqt, D_, D_);
        transpose_cast<<<tg, 256, 0, stream>>>(Wk, Wkt, D_, D_);
        transpose_cast<<<tg, 256, 0, stream>>>(Wv, Wvt, D_, D_);
        transpose_cast<<<tg, 256, 0, stream>>>(Wo, Wot, D_, D_);
        transpose_cast<<<tg, 256, 0, stream>>>(W1, W1t, D_, FF_);
        transpose_cast<<<tg, 256, 0, stream>>>(W2, W2t, FF_, D_);
        transpose_cast<<<dim3(16, 64, 1), 256, 0, stream>>>(Wsep, Wsept, IMG_, D_);
        int n = B_ * NH_ * IMG_;
        cast_bf16<<<(n + 255) / 256, 256, 0, stream>>>(sep_img, sep16, n);
    }

    auto run_encoder = [&](int M, int Tt, int lt, const int* lens_p) {
        int NT = M * Tt;
        dim3 gg(D_ / 128, NT / 128);
        int nqt = Tt / 64;
        for (int l = 0; l < L_; ++l) {
            size_t wl = (size_t)l * D_ * D_;
            gemm_mfma<bf16><<<gg, 256, 0, stream>>>(
                x16, Wqt + wl, bq + l * D_, qh, NT, D_, D_, lt, 0, 0);
            gemm_mfma<bf16><<<gg, 256, 0, stream>>>(
                x16, Wkt + wl, bk + l * D_, kh, NT, D_, D_, lt, 0, 0);
            gemm_mfma<bf16><<<gg, 256, 0, stream>>>(
                x16, Wvt + wl, bv + l * D_, vh, NT, D_, D_, lt, 0, 0);
            fused_attn<<<M * H_ * nqt, 256, 0, stream>>>(
                qh, kh, vh, ctx16, lens_p, Tt, nqt);
            gemm_mfma<float><<<gg, 256, 0, stream>>>(
                ctx16, Wot + wl, bo + l * D_, xb, NT, D_, D_, -1, 0, 1);
            ln_kernel<<<NT, 256, 0, stream>>>(xb, ln1g + l * D_, ln1b + l * D_, x16);
            gemm_mfma<bf16><<<gg, 256, 0, stream>>>(
                x16, W1t + wl, b1 + l * FF_, ffmid, NT, D_, FF_, -1, 1, 0);
            gemm_mfma<float><<<gg, 256, 0, stream>>>(
                ffmid, W2t + wl, b2 + l * D_, xb, NT, FF_, D_, -1, 0, 1);
            ln_kernel<<<NT, 256, 0, stream>>>(xb, ln2g + l * D_, ln2b + l * D_, x16);
        }
    };

    // ---- main encoder: M=64, Tt=256 (lt=8), no mask ----
    {
        int total = B_ * S_ * D_;
        embed_kernel<<<total / 256, 256, 0, stream>>>(segment, emb, xb, x16, S_, total);
    }
    run_encoder(B_, S_, 8, nullptr);
    copy_last_main<<<(B_ * D_) / 256, 256, 0, stream>>>(xb, bh);

    // ---- sep = separate_images @ Wsep + bsep : (384 x 2048) @ (2048 x 512) ----
    gemm_mfma<float><<<dim3(D_ / 128, (B_ * NH_) / 128), 256, 0, stream>>>(
        sep16, Wsept, bsep, sepb, B_ * NH_, D_, IMG_, -1, 0, 0);

    // ---- history encoder: M=384, Tt=64 (lt=6), key mask from lens ----
    {
        int total = B_ * NH_ * T_ * D_;
        embed_kernel<<<total / 256, 256, 0, stream>>>(prev_hist, emb, xb, x16, T_, total);
    }
    run_encoder(B_ * NH_, T_, 6, lens);

    add_last_kernel<<<(B_ * NH_ * D_) / 256, 256, 0, stream>>>(xb, lens, sepb);
    final_kernel<<<B_ * NH_, 256, 0, stream>>>(sepb, bh, normalize, out);
}

// Round 6
// 2628.074 us; speedup vs baseline: 7.3890x; 1.2401x over previous
//
#include <hip/hip_runtime.h>
#include <hip/hip_bf16.h>
#include <math.h>

typedef __hip_bfloat16 bf16;
typedef __attribute__((ext_vector_type(8))) short short8;
typedef __attribute__((ext_vector_type(4))) float f32x4;

#define D_    512
#define H_    4
#define DH_   128
#define L_    4
#define FF_   512
#define B_    64
#define NH_   6
#define S_    256
#define T_    64
#define IMG_  2048

__device__ __forceinline__ float toF(bf16 v)  { return __bfloat162float(v); }
__device__ __forceinline__ float toF(float v) { return v; }
__device__ __forceinline__ void storeF(bf16* p, float v)  { *p = __float2bfloat16(v); }
__device__ __forceinline__ void storeF(float* p, float v) { *p = v; }

// round-to-nearest-even f32 -> bf16 bits
__device__ __forceinline__ unsigned short f2b(float f) {
    unsigned u = __float_as_uint(f);
    unsigned r = (u + 0x7fffu + ((u >> 16) & 1u)) >> 16;
    return (unsigned short)r;
}

// ---- weight transpose + cast: src[R][C] fp32 -> dst[C][R] bf16, z = layer ----
__global__ void transpose_cast(const float* __restrict__ src, bf16* __restrict__ dst,
                               int R, int Cc) {
    __shared__ float t[32][33];
    size_t off = (size_t)blockIdx.z * R * Cc;
    src += off; dst += off;
    int c0 = blockIdx.x * 32, r0 = blockIdx.y * 32;
    int tx = threadIdx.x & 31, ty = threadIdx.x >> 5;  // 256 thr: ty 0..7
    for (int i = ty; i < 32; i += 8) t[i][tx] = src[(size_t)(r0 + i) * Cc + c0 + tx];
    __syncthreads();
    for (int i = ty; i < 32; i += 8)
        dst[(size_t)(c0 + i) * R + r0 + tx] = __float2bfloat16(t[tx][i]);
}

// ---- flat f32 -> bf16 cast ----
__global__ void cast_bf16(const float* __restrict__ src, bf16* __restrict__ dst, int n) {
    int i = blockIdx.x * blockDim.x + threadIdx.x;
    if (i < n) dst[i] = __float2bfloat16(src[i]);
}

// ---- embedding + positional encoding: fp32 x and bf16 mirror ----
__global__ void embed_kernel(const int* __restrict__ tokens,
                             const float* __restrict__ emb,
                             float* __restrict__ x, bf16* __restrict__ x16,
                             int Tt, int total) {
    int idx = blockIdx.x * blockDim.x + threadIdx.x;
    if (idx >= total) return;
    int d   = idx & (D_ - 1);
    int row = idx >> 9;
    int t   = row % Tt;
    int tok = tokens[row];
    int i   = d >> 1;
    float ex  = -(float)(2 * i) * (9.210340371976184f / 512.0f);
    float dv  = expf(ex);
    float ang = (float)t * dv;
    float pe  = (d & 1) ? cosf(ang) : sinf(ang);
    float v = emb[(size_t)tok * D_ + d] + pe;
    x[idx] = v;
    x16[idx] = __float2bfloat16(v);
}

// ---- MFMA bf16 GEMM: C[M,N] = A[M,K] @ B[K,N] + bias, B given transposed Bt[N][K]
// 128x128 tile, BK=64, 4 waves each computing 64x64 via 4x4 MFMAs 16x16x32.
// lt >= 0, vt=0: head-major bf16 out: out[((m*H+h)*Tt + qi)*128 + dh], Tt = 1<<lt
// lt >= 0, vt=1: head-major TRANSPOSED:  out[((m*H+h)*128 + dh)*Tt + qi]
// lt < 0 : row-major, optional addC (in-place +=) and relu.
template <typename CT>
__global__ __launch_bounds__(256) void gemm_mfma(
    const bf16* __restrict__ A, const bf16* __restrict__ Bt,
    const float* __restrict__ bias, CT* __restrict__ C,
    int M, int N, int K, int lt, int relu, int addC, int vt) {
    __shared__ short As[128][72];   // +8 shorts pad: 16B-aligned rows, 2-way-max banks
    __shared__ short Bs[128][72];
    int tid  = threadIdx.x;
    int wave = tid >> 6, lane = tid & 63, lr = lane & 15, quad = lane >> 4;
    int wr = (wave >> 1) * 64, wc = (wave & 1) * 64;
    int row0 = blockIdx.y * 128, col0 = blockIdx.x * 128;
    f32x4 acc[4][4];
    f32x4 zz = {0.f, 0.f, 0.f, 0.f};
#pragma unroll
    for (int mi = 0; mi < 4; ++mi)
#pragma unroll
        for (int ni = 0; ni < 4; ++ni) acc[mi][ni] = zz;

    for (int kt = 0; kt < K; kt += 64) {
        // stage 128x64 bf16 tiles: 1024 chunks of 8 shorts (16B), 4 per thread
#pragma unroll
        for (int ee = 0; ee < 4; ++ee) {
            int e = tid + ee * 256;       // 0..1023
            int r = e >> 3, c = (e & 7) * 8;
            *(short8*)&As[r][c] = *(const short8*)&A[(size_t)(row0 + r) * K + kt + c];
            *(short8*)&Bs[r][c] = *(const short8*)&Bt[(size_t)(col0 + r) * K + kt + c];
        }
        __syncthreads();
#pragma unroll
        for (int kk = 0; kk < 64; kk += 32) {
            short8 af[4], bf4[4];
#pragma unroll
            for (int mi = 0; mi < 4; ++mi)
                af[mi] = *(const short8*)&As[wr + mi * 16 + lr][kk + quad * 8];
#pragma unroll
            for (int ni = 0; ni < 4; ++ni)
                bf4[ni] = *(const short8*)&Bs[wc + ni * 16 + lr][kk + quad * 8];
#pragma unroll
            for (int mi = 0; mi < 4; ++mi)
#pragma unroll
                for (int ni = 0; ni < 4; ++ni)
                    acc[mi][ni] = __builtin_amdgcn_mfma_f32_16x16x32_bf16(
                        af[mi], bf4[ni], acc[mi][ni], 0, 0, 0);
        }
        __syncthreads();
    }
    int Ttm1 = (lt >= 0) ? ((1 << lt) - 1) : 0;
#pragma unroll
    for (int ni = 0; ni < 4; ++ni) {
        int gc = col0 + wc + ni * 16 + lr;
        float bi = bias[gc];
#pragma unroll
        for (int mi = 0; mi < 4; ++mi) {
            int gr0 = row0 + wr + mi * 16 + quad * 4;
            f32x4 vv = acc[mi][ni];
#pragma unroll
            for (int rr = 0; rr < 4; ++rr) {
                int r = gr0 + rr;
                float val = vv[rr] + bi;
                if (lt >= 0) {
                    int h2 = gc >> 7, dh = gc & 127;
                    int mq = r >> lt, qi = r & Ttm1;
                    size_t oi;
                    if (vt) oi = ((((size_t)(mq * H_ + h2)) * DH_ + dh) << lt) + qi;
                    else    oi = ((((size_t)(mq * H_ + h2)) << lt) + qi) * DH_ + dh;
                    storeF(&C[oi], val);
                } else {
                    size_t oi = (size_t)r * N + gc;
                    if (addC) val += toF(C[oi]);
                    if (relu) val = fmaxf(val, 0.f);
                    storeF(&C[oi], val);
                }
            }
        }
    }
}

// ---- MFMA flash attention: block per (m, h, 64-query tile), 256 threads = 4 waves.
// q,k head-major [mh][Tt][128] bf16; v TRANSPOSED [mh][128][Tt] bf16.
// ctx row-major [M*Tt][512] bf16. Each wave owns 16 queries.
__global__ __launch_bounds__(256) void fused_attn(
    const bf16* __restrict__ q, const bf16* __restrict__ k, const bf16* __restrict__ vt,
    bf16* __restrict__ ctx, const int* __restrict__ lens, int Tt, int nqt) {
    __shared__ short Ks[64][136];       // 64 keys x 128 dh (+8 pad: 2-way banks)
    __shared__ short Vs[128][72];       // 128 dh x 64 keys (+8 pad)
    __shared__ short Ps[4][16][72];     // per-wave P tile: 16 q x 64 keys (+8 pad)
    int bx = blockIdx.x;
    int qt = bx % nqt, mh = bx / nqt;
    int m = mh >> 2, h = mh & 3;
    int tid  = threadIdx.x;
    int wave = tid >> 6, lane = tid & 63, lr = lane & 15, quad = lane >> 4;
    int q0 = qt * 64;
    int kvalid = Tt;
    if (lens) { int l0 = lens[m]; kvalid = l0 < 1 ? 1 : l0; }

    // Q A-fragments (A[m=lr][kk=quad*8+j]), loaded once from global
    short8 aq[4];
    const bf16* qrow = q + ((size_t)mh * Tt + q0 + wave * 16 + lr) * DH_;
#pragma unroll
    for (int ks2 = 0; ks2 < 4; ++ks2)
        aq[ks2] = *(const short8*)&qrow[ks2 * 32 + quad * 8];

    float mrow[4], lrow[4];
#pragma unroll
    for (int r = 0; r < 4; ++r) { mrow[r] = -INFINITY; lrow[r] = 0.f; }
    f32x4 acco[8];
    f32x4 zz = {0.f, 0.f, 0.f, 0.f};
#pragma unroll
    for (int n = 0; n < 8; ++n) acco[n] = zz;

    int nkt = Tt >> 6;
    for (int kt = 0; kt < nkt; ++kt) {
        int kb = kt * 64;
        __syncthreads();   // protect Ks/Vs reuse from previous iteration
        // stage K tile: 64 x 128 shorts = 1024 16B chunks, 4/thread
#pragma unroll
        for (int ee = 0; ee < 4; ++ee) {
            int e = tid + ee * 256;
            int r = e >> 4, c = (e & 15) * 8;
            *(short8*)&Ks[r][c] = *(const short8*)&k[((size_t)mh * Tt + kb + r) * DH_ + c];
        }
        // stage V^T tile: 128 rows x 64 shorts = 1024 16B chunks, 4/thread
#pragma unroll
        for (int ee = 0; ee < 4; ++ee) {
            int e = tid + ee * 256;
            int r = e >> 3, c = (e & 7) * 8;
            *(short8*)&Vs[r][c] = *(const short8*)&vt[((size_t)mh * DH_ + r) * Tt + kb + c];
        }
        __syncthreads();
        // ---- S = Q K^T : 4 key-tiles x 4 K-steps of MFMA 16x16x32 ----
        f32x4 s[4];
#pragma unroll
        for (int ni = 0; ni < 4; ++ni) s[ni] = zz;
#pragma unroll
        for (int ni = 0; ni < 4; ++ni)
#pragma unroll
            for (int ks2 = 0; ks2 < 4; ++ks2) {
                short8 kf = *(const short8*)&Ks[ni * 16 + lr][ks2 * 32 + quad * 8];
                s[ni] = __builtin_amdgcn_mfma_f32_16x16x32_bf16(aq[ks2], kf, s[ni], 0, 0, 0);
            }
        // ---- scale + mask; per-lane col = kb + ni*16 + lr; rows = quad*4+reg ----
        float mx[4] = {-INFINITY, -INFINITY, -INFINITY, -INFINITY};
#pragma unroll
        for (int ni = 0; ni < 4; ++ni) {
            bool ok = (kb + ni * 16 + lr) < kvalid;
#pragma unroll
            for (int reg = 0; reg < 4; ++reg) {
                float v = s[ni][reg] * 0.08838834764831845f;
                v = ok ? v : -INFINITY;
                s[ni][reg] = v;
                mx[reg] = fmaxf(mx[reg], v);
            }
        }
        // row-max across the 16 lanes of the quad
#pragma unroll
        for (int d2 = 1; d2 < 16; d2 <<= 1)
#pragma unroll
            for (int reg = 0; reg < 4; ++reg)
                mx[reg] = fmaxf(mx[reg], __shfl_xor(mx[reg], d2));
        float alpha[4];
#pragma unroll
        for (int reg = 0; reg < 4; ++reg) {
            float mn = fmaxf(mrow[reg], mx[reg]);
            alpha[reg] = __expf(mrow[reg] - mn);
            mrow[reg] = mn;
        }
        // ---- P = exp(s - m); row sums; write P to per-wave LDS (A-layout source) ----
        float rs[4] = {0.f, 0.f, 0.f, 0.f};
#pragma unroll
        for (int ni = 0; ni < 4; ++ni)
#pragma unroll
            for (int reg = 0; reg < 4; ++reg) {
                float p = __expf(s[ni][reg] - mrow[reg]);   // exp(-inf - finite) = 0
                s[ni][reg] = p;
                rs[reg] += p;
            }
#pragma unroll
        for (int d2 = 1; d2 < 16; d2 <<= 1)
#pragma unroll
            for (int reg = 0; reg < 4; ++reg)
                rs[reg] += __shfl_xor(rs[reg], d2);
#pragma unroll
        for (int reg = 0; reg < 4; ++reg)
            lrow[reg] = lrow[reg] * alpha[reg] + rs[reg];
#pragma unroll
        for (int ni = 0; ni < 4; ++ni)
#pragma unroll
            for (int reg = 0; reg < 4; ++reg)
                Ps[wave][quad * 4 + reg][ni * 16 + lr] = (short)f2b(s[ni][reg]);
        // ---- rescale O accumulator, then O += P V ----
#pragma unroll
        for (int n = 0; n < 8; ++n)
#pragma unroll
            for (int reg = 0; reg < 4; ++reg) acco[n][reg] *= alpha[reg];
#pragma unroll
        for (int ks2 = 0; ks2 < 2; ++ks2) {
            short8 pf = *(const short8*)&Ps[wave][lr][ks2 * 32 + quad * 8];
#pragma unroll
            for (int n = 0; n < 8; ++n) {
                short8 vf = *(const short8*)&Vs[n * 16 + lr][ks2 * 32 + quad * 8];
                acco[n] = __builtin_amdgcn_mfma_f32_16x16x32_bf16(pf, vf, acco[n], 0, 0, 0);
            }
        }
    }
    // ---- epilogue: divide by l, store ctx row-major ----
    float linv[4];
#pragma unroll
    for (int reg = 0; reg < 4; ++reg) linv[reg] = 1.f / lrow[reg];
#pragma unroll
    for (int n = 0; n < 8; ++n)
#pragma unroll
        for (int reg = 0; reg < 4; ++reg) {
            int qq = q0 + wave * 16 + quad * 4 + reg;
            ctx[((size_t)m * Tt + qq) * D_ + h * DH_ + n * 16 + lr] =
                __float2bfloat16(acco[n][reg] * linv[reg]);
        }
}

// ---- LayerNorm in place (fp32) + bf16 mirror ----
__global__ void ln_kernel(float* __restrict__ x,
                          const float* __restrict__ g,
                          const float* __restrict__ b,
                          bf16* __restrict__ x16) {
    int row = blockIdx.x;
    int t   = threadIdx.x;
    __shared__ float red[256];
    float v0 = x[(size_t)row * D_ + t];
    float v1 = x[(size_t)row * D_ + t + 256];
    red[t] = v0 + v1;
    __syncthreads();
    for (int off = 128; off > 0; off >>= 1) {
        if (t < off) red[t] += red[t + off];
        __syncthreads();
    }
    float mu = red[0] / 512.f;
    __syncthreads();
    float d0 = v0 - mu, d1 = v1 - mu;
    red[t] = d0 * d0 + d1 * d1;
    __syncthreads();
    for (int off = 128; off > 0; off >>= 1) {
        if (t < off) red[t] += red[t + off];
        __syncthreads();
    }
    float inv = rsqrtf(red[0] / 512.f + 1e-5f);
    float o0 = d0 * inv * g[t] + b[t];
    float o1 = d1 * inv * g[t + 256] + b[t + 256];
    x[(size_t)row * D_ + t]       = o0;
    x[(size_t)row * D_ + t + 256] = o1;
    x16[(size_t)row * D_ + t]       = __float2bfloat16(o0);
    x16[(size_t)row * D_ + t + 256] = __float2bfloat16(o1);
}

__global__ void copy_last_main(const float* __restrict__ x, float* __restrict__ bh) {
    int idx = blockIdx.x * blockDim.x + threadIdx.x;  // 64*512
    int b = idx >> 9, d = idx & 511;
    bh[idx] = x[(size_t)(b * S_ + S_ - 1) * D_ + d];
}

__global__ void add_last_kernel(const float* __restrict__ x,
                                const int* __restrict__ lens,
                                float* __restrict__ sep) {
    int idx = blockIdx.x * blockDim.x + threadIdx.x;  // 384*512
    int bn = idx >> 9, d = idx & 511;
    int len = lens[bn];
    float add = (len > 0) ? x[(size_t)(bn * T_ + len - 1) * D_ + d] : 0.f;
    sep[idx] += add;
}

__global__ void final_kernel(const float* __restrict__ sep,
                             const float* __restrict__ bh,
                             const int* __restrict__ nflag,
                             float* __restrict__ out) {
    int bn = blockIdx.x;
    int b  = bn / NH_;
    int t  = threadIdx.x;  // 256
    __shared__ float red[256];
    float v0 = sep[(size_t)bn * D_ + t];
    float v1 = sep[(size_t)bn * D_ + t + 256];
    int nf = nflag[0];
    float scale = 1.f;
    if (nf) {
        v0 = fmaxf(v0, 0.f);
        v1 = fmaxf(v1, 0.f);
        red[t] = v0 * v0 + v1 * v1;
        __syncthreads();
        for (int off = 128; off > 0; off >>= 1) {
            if (t < off) red[t] += red[t + off];
            __syncthreads();
        }
        scale = 1.f / fmaxf(sqrtf(red[0]), 1e-12f);
        __syncthreads();
    }
    red[t] = v0 * scale * bh[(size_t)b * D_ + t] + v1 * scale * bh[(size_t)b * D_ + t + 256];
    __syncthreads();
    for (int off = 128; off > 0; off >>= 1) {
        if (t < off) red[t] += red[t + off];
        __syncthreads();
    }
    if (t == 0) out[bn] = red[0];
}

extern "C" void kernel_launch(void* const* d_in, const int* in_sizes, int n_in,
                              void* d_out, int out_size, void* d_ws, size_t ws_size,
                              hipStream_t stream) {
    const int*   segment   = (const int*)d_in[0];
    const int*   prev_hist = (const int*)d_in[1];
    const int*   lens      = (const int*)d_in[2];
    const float* sep_img   = (const float*)d_in[3];
    const int*   normalize = (const int*)d_in[4];
    const float* emb       = (const float*)d_in[5];
    const float* Wq = (const float*)d_in[6];
    const float* bq = (const float*)d_in[7];
    const float* Wk = (const float*)d_in[8];
    const float* bk = (const float*)d_in[9];
    const float* Wv = (const float*)d_in[10];
    const float* bv = (const float*)d_in[11];
    const float* Wo = (const float*)d_in[12];
    const float* bo = (const float*)d_in[13];
    const float* ln1g = (const float*)d_in[14];
    const float* ln1b = (const float*)d_in[15];
    const float* W1 = (const float*)d_in[16];
    const float* b1 = (const float*)d_in[17];
    const float* W2 = (const float*)d_in[18];
    const float* b2 = (const float*)d_in[19];
    const float* ln2g = (const float*)d_in[20];
    const float* ln2b = (const float*)d_in[21];
    const float* Wsep = (const float*)d_in[22];
    const float* bsep = (const float*)d_in[23];
    float* out = (float*)d_out;

    // ---- workspace layout (~160.4 MiB) ----
    const size_t NTmax = 384 * 64;  // 24576 (>= 64*256)
    char* w = (char*)d_ws;
    float* xb   = (float*)w; w += (size_t)NTmax * D_ * 4;   // fp32 residual stream
    float* bh   = (float*)w; w += (size_t)B_ * D_ * 4;
    float* sepb = (float*)w; w += (size_t)B_ * NH_ * D_ * 4;
    bf16* x16 = (bf16*)w; w += (size_t)NTmax * D_ * 2;      // bf16 mirror; also ctx
    bf16* qh  = (bf16*)w; w += (size_t)NTmax * D_ * 2;      // head-major q; also ffmid
    bf16* kh  = (bf16*)w; w += (size_t)NTmax * D_ * 2;
    bf16* vh  = (bf16*)w; w += (size_t)NTmax * D_ * 2;      // V^T head-major
    bf16* sep16 = (bf16*)w; w += (size_t)B_ * NH_ * IMG_ * 2;
    bf16* Wqt = (bf16*)w; w += (size_t)L_ * D_ * D_ * 2;
    bf16* Wkt = (bf16*)w; w += (size_t)L_ * D_ * D_ * 2;
    bf16* Wvt = (bf16*)w; w += (size_t)L_ * D_ * D_ * 2;
    bf16* Wot = (bf16*)w; w += (size_t)L_ * D_ * D_ * 2;
    bf16* W1t = (bf16*)w; w += (size_t)L_ * D_ * FF_ * 2;
    bf16* W2t = (bf16*)w; w += (size_t)L_ * FF_ * D_ * 2;
    bf16* Wsept = (bf16*)w; w += (size_t)IMG_ * D_ * 2;
    bf16* ctx16 = x16;   // alias: x16 not needed between qkv-GEMMs and LN1
    bf16* ffmid = qh;    // alias: q not needed after attention

    // ---- weight conversion (every call; inputs re-poisoned by harness) ----
    {
        dim3 tg(16, 16, L_);
        transpose_cast<<<tg, 256, 0, stream>>>(Wq, Wqt, D_, D_);
        transpose_cast<<<tg, 256, 0, stream>>>(Wk, Wkt, D_, D_);
        transpose_cast<<<tg, 256, 0, stream>>>(Wv, Wvt, D_, D_);
        transpose_cast<<<tg, 256, 0, stream>>>(Wo, Wot, D_, D_);
        transpose_cast<<<tg, 256, 0, stream>>>(W1, W1t, D_, FF_);
        transpose_cast<<<tg, 256, 0, stream>>>(W2, W2t, FF_, D_);
        transpose_cast<<<dim3(16, 64, 1), 256, 0, stream>>>(Wsep, Wsept, IMG_, D_);
        int n = B_ * NH_ * IMG_;
        cast_bf16<<<(n + 255) / 256, 256, 0, stream>>>(sep_img, sep16, n);
    }

    auto run_encoder = [&](int M, int Tt, int lt, const int* lens_p) {
        int NT = M * Tt;
        dim3 gg(D_ / 128, NT / 128);
        int nqt = Tt / 64;
        for (int l = 0; l < L_; ++l) {
            size_t wl = (size_t)l * D_ * D_;
            gemm_mfma<bf16><<<gg, 256, 0, stream>>>(
                x16, Wqt + wl, bq + l * D_, qh, NT, D_, D_, lt, 0, 0, 0);
            gemm_mfma<bf16><<<gg, 256, 0, stream>>>(
                x16, Wkt + wl, bk + l * D_, kh, NT, D_, D_, lt, 0, 0, 0);
            gemm_mfma<bf16><<<gg, 256, 0, stream>>>(
                x16, Wvt + wl, bv + l * D_, vh, NT, D_, D_, lt, 0, 0, 1);  // V^T
            fused_attn<<<M * H_ * nqt, 256, 0, stream>>>(
                qh, kh, vh, ctx16, lens_p, Tt, nqt);
            gemm_mfma<float><<<gg, 256, 0, stream>>>(
                ctx16, Wot + wl, bo + l * D_, xb, NT, D_, D_, -1, 0, 1, 0);
            ln_kernel<<<NT, 256, 0, stream>>>(xb, ln1g + l * D_, ln1b + l * D_, x16);
            gemm_mfma<bf16><<<gg, 256, 0, stream>>>(
                x16, W1t + wl, b1 + l * FF_, ffmid, NT, D_, FF_, -1, 1, 0, 0);
            gemm_mfma<float><<<gg, 256, 0, stream>>>(
                ffmid, W2t + wl, b2 + l * D_, xb, NT, FF_, D_, -1, 0, 1, 0);
            ln_kernel<<<NT, 256, 0, stream>>>(xb, ln2g + l * D_, ln2b + l * D_, x16);
        }
    };

    // ---- main encoder: M=64, Tt=256 (lt=8), no mask ----
    {
        int total = B_ * S_ * D_;
        embed_kernel<<<total / 256, 256, 0, stream>>>(segment, emb, xb, x16, S_, total);
    }
    run_encoder(B_, S_, 8, nullptr);
    copy_last_main<<<(B_ * D_) / 256, 256, 0, stream>>>(xb, bh);

    // ---- sep = separate_images @ Wsep + bsep : (384 x 2048) @ (2048 x 512) ----
    gemm_mfma<float><<<dim3(D_ / 128, (B_ * NH_) / 128), 256, 0, stream>>>(
        sep16, Wsept, bsep, sepb, B_ * NH_, D_, IMG_, -1, 0, 0, 0);

    // ---- history encoder: M=384, Tt=64 (lt=6), key mask from lens ----
    {
        int total = B_ * NH_ * T_ * D_;
        embed_kernel<<<total / 256, 256, 0, stream>>>(prev_hist, emb, xb, x16, T_, total);
    }
    run_encoder(B_ * NH_, T_, 6, lens);

    add_last_kernel<<<(B_ * NH_ * D_) / 256, 256, 0, stream>>>(xb, lens, sepb);
    final_kernel<<<B_ * NH_, 256, 0, stream>>>(sepb, bh, normalize, out);
}

// Round 7
// 2481.750 us; speedup vs baseline: 7.8247x; 1.0590x over previous
//
#include <hip/hip_runtime.h>
#include <hip/hip_bf16.h>
#include <math.h>

typedef __hip_bfloat16 bf16;
typedef __attribute__((ext_vector_type(8))) short short8;
typedef __attribute__((ext_vector_type(4))) float f32x4;

#define D_    512
#define H_    4
#define DH_   128
#define L_    4
#define FF_   512
#define B_    64
#define NH_   6
#define S_    256
#define T_    64
#define IMG_  2048

__device__ __forceinline__ float toF(bf16 v)  { return __bfloat162float(v); }
__device__ __forceinline__ float toF(float v) { return v; }
__device__ __forceinline__ void storeF(bf16* p, float v)  { *p = __float2bfloat16(v); }
__device__ __forceinline__ void storeF(float* p, float v) { *p = v; }

// round-to-nearest-even f32 -> bf16 bits
__device__ __forceinline__ unsigned short f2b(float f) {
    unsigned u = __float_as_uint(f);
    unsigned r = (u + 0x7fffu + ((u >> 16) & 1u)) >> 16;
    return (unsigned short)r;
}

// ---- weight transpose + cast: src[R][C] fp32 -> dst[C][R] bf16, z = layer ----
__global__ void transpose_cast(const float* __restrict__ src, bf16* __restrict__ dst,
                               int R, int Cc) {
    __shared__ float t[32][33];
    size_t off = (size_t)blockIdx.z * R * Cc;
    src += off; dst += off;
    int c0 = blockIdx.x * 32, r0 = blockIdx.y * 32;
    int tx = threadIdx.x & 31, ty = threadIdx.x >> 5;  // 256 thr: ty 0..7
    for (int i = ty; i < 32; i += 8) t[i][tx] = src[(size_t)(r0 + i) * Cc + c0 + tx];
    __syncthreads();
    for (int i = ty; i < 32; i += 8)
        dst[(size_t)(c0 + i) * R + r0 + tx] = __float2bfloat16(t[tx][i]);
}

// ---- flat f32 -> bf16 cast ----
__global__ void cast_bf16(const float* __restrict__ src, bf16* __restrict__ dst, int n) {
    int i = blockIdx.x * blockDim.x + threadIdx.x;
    if (i < n) dst[i] = __float2bfloat16(src[i]);
}

// ---- embedding + positional encoding: bf16 out ----
__global__ void embed_kernel(const int* __restrict__ tokens,
                             const float* __restrict__ emb,
                             bf16* __restrict__ x16,
                             int Tt, int total) {
    int idx = blockIdx.x * blockDim.x + threadIdx.x;
    if (idx >= total) return;
    int d   = idx & (D_ - 1);
    int row = idx >> 9;
    int t   = row % Tt;
    int tok = tokens[row];
    int i   = d >> 1;
    float ex  = -(float)(2 * i) * (9.210340371976184f / 512.0f);
    float dv  = expf(ex);
    float ang = (float)t * dv;
    float pe  = (d & 1) ? cosf(ang) : sinf(ang);
    x16[idx] = __float2bfloat16(emb[(size_t)tok * D_ + d] + pe);
}

// ---- MFMA bf16 GEMM: C[M,N] = A[M,K] @ B[K,N] + bias, B given transposed Bt[N][K]
// 128x128 tile, BK=64, 4 waves each computing 64x64 via 4x4 MFMAs 16x16x32.
// lt >= 0, vt=0: head-major bf16 out: out[((m*H+h)*Tt + qi)*128 + dh], Tt = 1<<lt
// lt >= 0, vt=1: head-major TRANSPOSED:  out[((m*H+h)*128 + dh)*Tt + qi]
// lt < 0 : row-major, optional addC (in-place += on bf16/f32 C) and relu.
// XCD swizzle: when gridDim.y % 8 == 0, remap blocks so all gridDim.x N-blocks
// of one row-panel land on one XCD (same id%8) for A-panel L2 locality.
template <typename CT>
__global__ __launch_bounds__(256) void gemm_mfma(
    const bf16* __restrict__ A, const bf16* __restrict__ Bt,
    const float* __restrict__ bias, CT* __restrict__ C,
    int M, int N, int K, int lt, int relu, int addC, int vt) {
    __shared__ short As[128][72];   // +8 shorts pad: 16B-aligned rows, 2-way-max banks
    __shared__ short Bs[128][72];
    int tid  = threadIdx.x;
    int wave = tid >> 6, lane = tid & 63, lr = lane & 15, quad = lane >> 4;
    int wr = (wave >> 1) * 64, wc = (wave & 1) * 64;
    int bx = blockIdx.x, by = blockIdx.y;
    if ((gridDim.y & 7) == 0) {
        int id = by * gridDim.x + bx;
        int xcd = id & 7, slot = id >> 3;
        by = xcd + 8 * (slot / gridDim.x);
        bx = slot % gridDim.x;
    }
    int row0 = by * 128, col0 = bx * 128;
    f32x4 acc[4][4];
    f32x4 zz = {0.f, 0.f, 0.f, 0.f};
#pragma unroll
    for (int mi = 0; mi < 4; ++mi)
#pragma unroll
        for (int ni = 0; ni < 4; ++ni) acc[mi][ni] = zz;

    for (int kt = 0; kt < K; kt += 64) {
        // stage 128x64 bf16 tiles: 1024 chunks of 8 shorts (16B), 4 per thread
#pragma unroll
        for (int ee = 0; ee < 4; ++ee) {
            int e = tid + ee * 256;       // 0..1023
            int r = e >> 3, c = (e & 7) * 8;
            *(short8*)&As[r][c] = *(const short8*)&A[(size_t)(row0 + r) * K + kt + c];
            *(short8*)&Bs[r][c] = *(const short8*)&Bt[(size_t)(col0 + r) * K + kt + c];
        }
        __syncthreads();
#pragma unroll
        for (int kk = 0; kk < 64; kk += 32) {
            short8 af[4], bf4[4];
#pragma unroll
            for (int mi = 0; mi < 4; ++mi)
                af[mi] = *(const short8*)&As[wr + mi * 16 + lr][kk + quad * 8];
#pragma unroll
            for (int ni = 0; ni < 4; ++ni)
                bf4[ni] = *(const short8*)&Bs[wc + ni * 16 + lr][kk + quad * 8];
#pragma unroll
            for (int mi = 0; mi < 4; ++mi)
#pragma unroll
                for (int ni = 0; ni < 4; ++ni)
                    acc[mi][ni] = __builtin_amdgcn_mfma_f32_16x16x32_bf16(
                        af[mi], bf4[ni], acc[mi][ni], 0, 0, 0);
        }
        __syncthreads();
    }
    int Ttm1 = (lt >= 0) ? ((1 << lt) - 1) : 0;
#pragma unroll
    for (int ni = 0; ni < 4; ++ni) {
        int gc = col0 + wc + ni * 16 + lr;
        float bi = bias[gc];
#pragma unroll
        for (int mi = 0; mi < 4; ++mi) {
            int gr0 = row0 + wr + mi * 16 + quad * 4;
            f32x4 vv = acc[mi][ni];
#pragma unroll
            for (int rr = 0; rr < 4; ++rr) {
                int r = gr0 + rr;
                float val = vv[rr] + bi;
                if (lt >= 0) {
                    int h2 = gc >> 7, dh = gc & 127;
                    int mq = r >> lt, qi = r & Ttm1;
                    size_t oi;
                    if (vt) oi = ((((size_t)(mq * H_ + h2)) * DH_ + dh) << lt) + qi;
                    else    oi = ((((size_t)(mq * H_ + h2)) << lt) + qi) * DH_ + dh;
                    storeF(&C[oi], val);
                } else {
                    size_t oi = (size_t)r * N + gc;
                    if (addC) val += toF(C[oi]);
                    if (relu) val = fmaxf(val, 0.f);
                    storeF(&C[oi], val);
                }
            }
        }
    }
}

// ---- MFMA flash attention: block per (m, h, 64-query tile), 256 threads = 4 waves.
// q,k head-major [mh][Tt][128] bf16; v TRANSPOSED [mh][128][Tt] bf16.
// ctx row-major [M*Tt][512] bf16. Each wave owns 16 queries.
__global__ __launch_bounds__(256) void fused_attn(
    const bf16* __restrict__ q, const bf16* __restrict__ k, const bf16* __restrict__ vt,
    bf16* __restrict__ ctx, const int* __restrict__ lens, int Tt, int nqt) {
    __shared__ short Ks[64][136];       // 64 keys x 128 dh (+8 pad: 2-way banks)
    __shared__ short Vs[128][72];       // 128 dh x 64 keys (+8 pad)
    __shared__ short Ps[4][16][72];     // per-wave P tile: 16 q x 64 keys (+8 pad)
    int bx = blockIdx.x;
    int qt = bx % nqt, mh = bx / nqt;
    int m = mh >> 2, h = mh & 3;
    int tid  = threadIdx.x;
    int wave = tid >> 6, lane = tid & 63, lr = lane & 15, quad = lane >> 4;
    int q0 = qt * 64;
    int kvalid = Tt;
    if (lens) { int l0 = lens[m]; kvalid = l0 < 1 ? 1 : l0; }

    // Q A-fragments (A[m=lr][kk=quad*8+j]), loaded once from global
    short8 aq[4];
    const bf16* qrow = q + ((size_t)mh * Tt + q0 + wave * 16 + lr) * DH_;
#pragma unroll
    for (int ks2 = 0; ks2 < 4; ++ks2)
        aq[ks2] = *(const short8*)&qrow[ks2 * 32 + quad * 8];

    float mrow[4], lrow[4];
#pragma unroll
    for (int r = 0; r < 4; ++r) { mrow[r] = -INFINITY; lrow[r] = 0.f; }
    f32x4 acco[8];
    f32x4 zz = {0.f, 0.f, 0.f, 0.f};
#pragma unroll
    for (int n = 0; n < 8; ++n) acco[n] = zz;

    int nkt = Tt >> 6;
    for (int kt = 0; kt < nkt; ++kt) {
        int kb = kt * 64;
        __syncthreads();   // protect Ks/Vs reuse from previous iteration
        // stage K tile: 64 x 128 shorts = 1024 16B chunks, 4/thread
#pragma unroll
        for (int ee = 0; ee < 4; ++ee) {
            int e = tid + ee * 256;
            int r = e >> 4, c = (e & 15) * 8;
            *(short8*)&Ks[r][c] = *(const short8*)&k[((size_t)mh * Tt + kb + r) * DH_ + c];
        }
        // stage V^T tile: 128 rows x 64 shorts = 1024 16B chunks, 4/thread
#pragma unroll
        for (int ee = 0; ee < 4; ++ee) {
            int e = tid + ee * 256;
            int r = e >> 3, c = (e & 7) * 8;
            *(short8*)&Vs[r][c] = *(const short8*)&vt[((size_t)mh * DH_ + r) * Tt + kb + c];
        }
        __syncthreads();
        // ---- S = Q K^T : 4 key-tiles x 4 K-steps of MFMA 16x16x32 ----
        f32x4 s[4];
#pragma unroll
        for (int ni = 0; ni < 4; ++ni) s[ni] = zz;
#pragma unroll
        for (int ni = 0; ni < 4; ++ni)
#pragma unroll
            for (int ks2 = 0; ks2 < 4; ++ks2) {
                short8 kf = *(const short8*)&Ks[ni * 16 + lr][ks2 * 32 + quad * 8];
                s[ni] = __builtin_amdgcn_mfma_f32_16x16x32_bf16(aq[ks2], kf, s[ni], 0, 0, 0);
            }
        // ---- scale + mask; per-lane col = kb + ni*16 + lr; rows = quad*4+reg ----
        float mx[4] = {-INFINITY, -INFINITY, -INFINITY, -INFINITY};
#pragma unroll
        for (int ni = 0; ni < 4; ++ni) {
            bool ok = (kb + ni * 16 + lr) < kvalid;
#pragma unroll
            for (int reg = 0; reg < 4; ++reg) {
                float v = s[ni][reg] * 0.08838834764831845f;
                v = ok ? v : -INFINITY;
                s[ni][reg] = v;
                mx[reg] = fmaxf(mx[reg], v);
            }
        }
        // row-max across the 16 lanes of the quad
#pragma unroll
        for (int d2 = 1; d2 < 16; d2 <<= 1)
#pragma unroll
            for (int reg = 0; reg < 4; ++reg)
                mx[reg] = fmaxf(mx[reg], __shfl_xor(mx[reg], d2));
        float alpha[4];
#pragma unroll
        for (int reg = 0; reg < 4; ++reg) {
            float mn = fmaxf(mrow[reg], mx[reg]);
            alpha[reg] = __expf(mrow[reg] - mn);
            mrow[reg] = mn;
        }
        // ---- P = exp(s - m); row sums; write P to per-wave LDS (A-layout source) ----
        float rs[4] = {0.f, 0.f, 0.f, 0.f};
#pragma unroll
        for (int ni = 0; ni < 4; ++ni)
#pragma unroll
            for (int reg = 0; reg < 4; ++reg) {
                float p = __expf(s[ni][reg] - mrow[reg]);   // exp(-inf - finite) = 0
                s[ni][reg] = p;
                rs[reg] += p;
            }
#pragma unroll
        for (int d2 = 1; d2 < 16; d2 <<= 1)
#pragma unroll
            for (int reg = 0; reg < 4; ++reg)
                rs[reg] += __shfl_xor(rs[reg], d2);
#pragma unroll
        for (int reg = 0; reg < 4; ++reg)
            lrow[reg] = lrow[reg] * alpha[reg] + rs[reg];
#pragma unroll
        for (int ni = 0; ni < 4; ++ni)
#pragma unroll
            for (int reg = 0; reg < 4; ++reg)
                Ps[wave][quad * 4 + reg][ni * 16 + lr] = (short)f2b(s[ni][reg]);
        // ---- rescale O accumulator, then O += P V ----
#pragma unroll
        for (int n = 0; n < 8; ++n)
#pragma unroll
            for (int reg = 0; reg < 4; ++reg) acco[n][reg] *= alpha[reg];
#pragma unroll
        for (int ks2 = 0; ks2 < 2; ++ks2) {
            short8 pf = *(const short8*)&Ps[wave][lr][ks2 * 32 + quad * 8];
#pragma unroll
            for (int n = 0; n < 8; ++n) {
                short8 vf = *(const short8*)&Vs[n * 16 + lr][ks2 * 32 + quad * 8];
                acco[n] = __builtin_amdgcn_mfma_f32_16x16x32_bf16(pf, vf, acco[n], 0, 0, 0);
            }
        }
    }
    // ---- epilogue: divide by l, store ctx row-major ----
    float linv[4];
#pragma unroll
    for (int reg = 0; reg < 4; ++reg) linv[reg] = 1.f / lrow[reg];
#pragma unroll
    for (int n = 0; n < 8; ++n)
#pragma unroll
        for (int reg = 0; reg < 4; ++reg) {
            int qq = q0 + wave * 16 + quad * 4 + reg;
            ctx[((size_t)m * Tt + qq) * D_ + h * DH_ + n * 16 + lr] =
                __float2bfloat16(acco[n][reg] * linv[reg]);
        }
}

// ---- LayerNorm in place on bf16 (fp32 stats) ----
__global__ void ln_kernel(bf16* __restrict__ x,
                          const float* __restrict__ g,
                          const float* __restrict__ b) {
    int row = blockIdx.x;
    int t   = threadIdx.x;
    __shared__ float red[256];
    float v0 = toF(x[(size_t)row * D_ + t]);
    float v1 = toF(x[(size_t)row * D_ + t + 256]);
    red[t] = v0 + v1;
    __syncthreads();
    for (int off = 128; off > 0; off >>= 1) {
        if (t < off) red[t] += red[t + off];
        __syncthreads();
    }
    float mu = red[0] / 512.f;
    __syncthreads();
    float d0 = v0 - mu, d1 = v1 - mu;
    red[t] = d0 * d0 + d1 * d1;
    __syncthreads();
    for (int off = 128; off > 0; off >>= 1) {
        if (t < off) red[t] += red[t + off];
        __syncthreads();
    }
    float inv = rsqrtf(red[0] / 512.f + 1e-5f);
    x[(size_t)row * D_ + t]       = __float2bfloat16(d0 * inv * g[t] + b[t]);
    x[(size_t)row * D_ + t + 256] = __float2bfloat16(d1 * inv * g[t + 256] + b[t + 256]);
}

__global__ void copy_last_main(const bf16* __restrict__ x, float* __restrict__ bh) {
    int idx = blockIdx.x * blockDim.x + threadIdx.x;  // 64*512
    int b = idx >> 9, d = idx & 511;
    bh[idx] = toF(x[(size_t)(b * S_ + S_ - 1) * D_ + d]);
}

__global__ void add_last_kernel(const bf16* __restrict__ x,
                                const int* __restrict__ lens,
                                float* __restrict__ sep) {
    int idx = blockIdx.x * blockDim.x + threadIdx.x;  // 384*512
    int bn = idx >> 9, d = idx & 511;
    int len = lens[bn];
    float add = (len > 0) ? toF(x[(size_t)(bn * T_ + len - 1) * D_ + d]) : 0.f;
    sep[idx] += add;
}

__global__ void final_kernel(const float* __restrict__ sep,
                             const float* __restrict__ bh,
                             const int* __restrict__ nflag,
                             float* __restrict__ out) {
    int bn = blockIdx.x;
    int b  = bn / NH_;
    int t  = threadIdx.x;  // 256
    __shared__ float red[256];
    float v0 = sep[(size_t)bn * D_ + t];
    float v1 = sep[(size_t)bn * D_ + t + 256];
    int nf = nflag[0];
    float scale = 1.f;
    if (nf) {
        v0 = fmaxf(v0, 0.f);
        v1 = fmaxf(v1, 0.f);
        red[t] = v0 * v0 + v1 * v1;
        __syncthreads();
        for (int off = 128; off > 0; off >>= 1) {
            if (t < off) red[t] += red[t + off];
            __syncthreads();
        }
        scale = 1.f / fmaxf(sqrtf(red[0]), 1e-12f);
        __syncthreads();
    }
    red[t] = v0 * scale * bh[(size_t)b * D_ + t] + v1 * scale * bh[(size_t)b * D_ + t + 256];
    __syncthreads();
    for (int off = 128; off > 0; off >>= 1) {
        if (t < off) red[t] += red[t + off];
        __syncthreads();
    }
    if (t == 0) out[bn] = red[0];
}

extern "C" void kernel_launch(void* const* d_in, const int* in_sizes, int n_in,
                              void* d_out, int out_size, void* d_ws, size_t ws_size,
                              hipStream_t stream) {
    const int*   segment   = (const int*)d_in[0];
    const int*   prev_hist = (const int*)d_in[1];
    const int*   lens      = (const int*)d_in[2];
    const float* sep_img   = (const float*)d_in[3];
    const int*   normalize = (const int*)d_in[4];
    const float* emb       = (const float*)d_in[5];
    const float* Wq = (const float*)d_in[6];
    const float* bq = (const float*)d_in[7];
    const float* Wk = (const float*)d_in[8];
    const float* bk = (const float*)d_in[9];
    const float* Wv = (const float*)d_in[10];
    const float* bv = (const float*)d_in[11];
    const float* Wo = (const float*)d_in[12];
    const float* bo = (const float*)d_in[13];
    const float* ln1g = (const float*)d_in[14];
    const float* ln1b = (const float*)d_in[15];
    const float* W1 = (const float*)d_in[16];
    const float* b1 = (const float*)d_in[17];
    const float* W2 = (const float*)d_in[18];
    const float* b2 = (const float*)d_in[19];
    const float* ln2g = (const float*)d_in[20];
    const float* ln2b = (const float*)d_in[21];
    const float* Wsep = (const float*)d_in[22];
    const float* bsep = (const float*)d_in[23];
    float* out = (float*)d_out;

    // ---- workspace layout (~142 MiB) ----
    const size_t NTmax = 384 * 64;  // 24576 (>= 64*256)
    char* w = (char*)d_ws;
    float* bh   = (float*)w; w += (size_t)B_ * D_ * 4;
    float* sepb = (float*)w; w += (size_t)B_ * NH_ * D_ * 4;
    bf16* x16 = (bf16*)w; w += (size_t)NTmax * D_ * 2;      // bf16 residual stream
    bf16* ctxb = (bf16*)w; w += (size_t)NTmax * D_ * 2;     // attention context
    bf16* qh  = (bf16*)w; w += (size_t)NTmax * D_ * 2;      // head-major q; also ffmid
    bf16* kh  = (bf16*)w; w += (size_t)NTmax * D_ * 2;
    bf16* vh  = (bf16*)w; w += (size_t)NTmax * D_ * 2;      // V^T head-major
    bf16* sep16 = (bf16*)w; w += (size_t)B_ * NH_ * IMG_ * 2;
    bf16* Wqt = (bf16*)w; w += (size_t)L_ * D_ * D_ * 2;
    bf16* Wkt = (bf16*)w; w += (size_t)L_ * D_ * D_ * 2;
    bf16* Wvt = (bf16*)w; w += (size_t)L_ * D_ * D_ * 2;
    bf16* Wot = (bf16*)w; w += (size_t)L_ * D_ * D_ * 2;
    bf16* W1t = (bf16*)w; w += (size_t)L_ * D_ * FF_ * 2;
    bf16* W2t = (bf16*)w; w += (size_t)L_ * FF_ * D_ * 2;
    bf16* Wsept = (bf16*)w; w += (size_t)IMG_ * D_ * 2;
    bf16* ffmid = qh;    // alias: q not needed after attention

    // ---- weight conversion (every call; inputs re-poisoned by harness) ----
    {
        dim3 tg(16, 16, L_);
        transpose_cast<<<tg, 256, 0, stream>>>(Wq, Wqt, D_, D_);
        transpose_cast<<<tg, 256, 0, stream>>>(Wk, Wkt, D_, D_);
        transpose_cast<<<tg, 256, 0, stream>>>(Wv, Wvt, D_, D_);
        transpose_cast<<<tg, 256, 0, stream>>>(Wo, Wot, D_, D_);
        transpose_cast<<<tg, 256, 0, stream>>>(W1, W1t, D_, FF_);
        transpose_cast<<<tg, 256, 0, stream>>>(W2, W2t, FF_, D_);
        transpose_cast<<<dim3(16, 64, 1), 256, 0, stream>>>(Wsep, Wsept, IMG_, D_);
        int n = B_ * NH_ * IMG_;
        cast_bf16<<<(n + 255) / 256, 256, 0, stream>>>(sep_img, sep16, n);
    }

    auto run_encoder = [&](int M, int Tt, int lt, const int* lens_p) {
        int NT = M * Tt;
        dim3 gg(D_ / 128, NT / 128);
        int nqt = Tt / 64;
        for (int l = 0; l < L_; ++l) {
            size_t wl = (size_t)l * D_ * D_;
            gemm_mfma<bf16><<<gg, 256, 0, stream>>>(
                x16, Wqt + wl, bq + l * D_, qh, NT, D_, D_, lt, 0, 0, 0);
            gemm_mfma<bf16><<<gg, 256, 0, stream>>>(
                x16, Wkt + wl, bk + l * D_, kh, NT, D_, D_, lt, 0, 0, 0);
            gemm_mfma<bf16><<<gg, 256, 0, stream>>>(
                x16, Wvt + wl, bv + l * D_, vh, NT, D_, D_, lt, 0, 0, 1);  // V^T
            fused_attn<<<M * H_ * nqt, 256, 0, stream>>>(
                qh, kh, vh, ctxb, lens_p, Tt, nqt);
            gemm_mfma<bf16><<<gg, 256, 0, stream>>>(
                ctxb, Wot + wl, bo + l * D_, x16, NT, D_, D_, -1, 0, 1, 0);  // += resid
            ln_kernel<<<NT, 256, 0, stream>>>(x16, ln1g + l * D_, ln1b + l * D_);
            gemm_mfma<bf16><<<gg, 256, 0, stream>>>(
                x16, W1t + wl, b1 + l * FF_, ffmid, NT, D_, FF_, -1, 1, 0, 0);
            gemm_mfma<bf16><<<gg, 256, 0, stream>>>(
                ffmid, W2t + wl, b2 + l * D_, x16, NT, FF_, D_, -1, 0, 1, 0); // += resid
            ln_kernel<<<NT, 256, 0, stream>>>(x16, ln2g + l * D_, ln2b + l * D_);
        }
    };

    // ---- main encoder: M=64, Tt=256 (lt=8), no mask ----
    {
        int total = B_ * S_ * D_;
        embed_kernel<<<total / 256, 256, 0, stream>>>(segment, emb, x16, S_, total);
    }
    run_encoder(B_, S_, 8, nullptr);
    copy_last_main<<<(B_ * D_) / 256, 256, 0, stream>>>(x16, bh);

    // ---- sep = separate_images @ Wsep + bsep : (384 x 2048) @ (2048 x 512) ----
    gemm_mfma<float><<<dim3(D_ / 128, (B_ * NH_) / 128), 256, 0, stream>>>(
        sep16, Wsept, bsep, sepb, B_ * NH_, D_, IMG_, -1, 0, 0, 0);

    // ---- history encoder: M=384, Tt=64 (lt=6), key mask from lens ----
    {
        int total = B_ * NH_ * T_ * D_;
        embed_kernel<<<total / 256, 256, 0, stream>>>(prev_hist, emb, x16, T_, total);
    }
    run_encoder(B_ * NH_, T_, 6, lens);

    add_last_kernel<<<(B_ * NH_ * D_) / 256, 256, 0, stream>>>(x16, lens, sepb);
    final_kernel<<<B_ * NH_, 256, 0, stream>>>(sepb, bh, normalize, out);
}